// Round 14
// baseline (7618.806 us; speedup 1.0000x reference)
//
#include <hip/hip_runtime.h>
#include <hip/hip_bf16.h>

typedef short short8 __attribute__((ext_vector_type(8)));
typedef float f32x4 __attribute__((ext_vector_type(4)));

#define BROWS 64
#define NTHR  512
#define XK    96
#define XSTR  104
#define HSTR  264
#define HIDSTR 129
#define NKT0  11
#define NKT1  16
#define NKTO  8
#define PK0_ELEMS (64*NKT0*512)
#define PK1_ELEMS (64*NKT1*512)
#define PKO_ELEMS (8*NKTO*512)

// c-state workspace: 256 blocks x 4 passes x 4 chunks x 512 thr x float4
#define CWS_OFF_BYTES (2*1024*1024)          // weights occupy first 1.91MB of d_ws
#define CWS_FLOATS ((size_t)256*4*4*NTHR*4)  // 33.5MB
#define WS_NEED (CWS_OFF_BYTES + CWS_FLOATS*4)

// LDS layout (bytes) — 149,264 B, STATIC
#define L_X    0
#define L_H    13312
#define HBUF   (BROWS*HSTR)
#define HBUF_B (HBUF*2)
#define L_HID  (L_H + 3*HBUF_B)      // 114688 : [64][129] f32
#define L_OW2  (L_HID + BROWS*HIDSTR*4) // 147712
#define L_OB2  (L_OW2 + 1536)        // 149248
#define LDS_TOTAL 149264

__device__ inline unsigned short f2bf(float x){
  unsigned u = __float_as_uint(x);
  u += 0x7FFFu + ((u >> 16) & 1u);
  return (unsigned short)(u >> 16);
}
__device__ inline float bf2f(unsigned short s){ return __uint_as_float(((unsigned)s) << 16); }
__device__ inline float sigm(float x){ return 1.f / (1.f + __expf(-x)); }
__device__ inline float ftanh(float x){ float e = __expf(2.f*x); return 1.f - 2.f/(e + 1.f); }

// ---------------- weight pre-pack (identical to R13) ----------------
__global__ void pack_weights(const float* __restrict__ wih0, const float* __restrict__ whh0,
                             const float* __restrict__ bih0, const float* __restrict__ bhh0,
                             const float* __restrict__ wih1, const float* __restrict__ whh1,
                             const float* __restrict__ ow1,
                             unsigned short* __restrict__ wsb){
  int idx = blockIdx.x * blockDim.x + threadIdx.x;
  int total = PK0_ELEMS + PK1_ELEMS + PKO_ELEMS;
  if (idx >= total) return;
  float w;
  size_t off;
  if (idx < PK0_ELEMS) {
    int nt = idx / (NKT0*512), rem = idx % (NKT0*512), kt = rem / 512, li = rem % 512;
    int lane = li >> 3, j = li & 7;
    int n = lane & 15, k = ((lane >> 4) << 3) + j;
    int Kg = kt*32 + k, g = nt*16 + n;
    if (Kg < 73)        w = wih0[g*73 + Kg];
    else if (Kg == 73)  w = bih0[g] + bhh0[g];
    else if (Kg < XK)   w = 0.f;
    else                w = whh0[g*256 + (Kg - XK)];
    off = ((size_t)(nt*NKT0 + kt)*64 + lane)*8 + j;
  } else if (idx < PK0_ELEMS + PK1_ELEMS) {
    int i2 = idx - PK0_ELEMS;
    int nt = i2 / (NKT1*512), rem = i2 % (NKT1*512), kt = rem / 512, li = rem % 512;
    int lane = li >> 3, j = li & 7;
    int n = lane & 15, k = ((lane >> 4) << 3) + j;
    int Kg = kt*32 + k, g = nt*16 + n;
    w = (Kg < 256) ? wih1[g*256 + Kg] : whh1[g*256 + (Kg - 256)];
    off = (size_t)PK0_ELEMS + ((size_t)(nt*NKT1 + kt)*64 + lane)*8 + j;
  } else {
    int i2 = idx - PK0_ELEMS - PK1_ELEMS;
    int nt = i2 / (NKTO*512), rem = i2 % (NKTO*512), kt = rem / 512, li = rem % 512;
    int lane = li >> 3, j = li & 7;
    int n = lane & 15, k = ((lane >> 4) << 3) + j;
    int Kg = kt*32 + k, uh = nt*16 + n;
    w = ow1[uh*256 + Kg];
    off = (size_t)PK0_ELEMS + (size_t)PK1_ELEMS + ((size_t)(nt*NKTO + kt)*64 + lane)*8 + j;
  }
  wsb[off] = f2bf(w);
}

// ---------------- persistent rollout kernel ----------------
// R1-R13: VGPR cap = 65536/NTHR, immutable by any attribute. At BROWS=64 the
// problem state acc(64)+c(64) = the whole 128 file -> forced spills -> L2 scratch
// pollution -> 50% weight miss -> latency-bound. CWS=1: c-state round-trips
// through d_ws with NONTEMPORAL float4 ld/st (no L2 allocation), loaded at pass
// start (latency hidden under the pass), freeing ~50 regs. CWS=0: R13 fallback.
template<int CWS>
__global__ void __launch_bounds__(NTHR)
traj_main(const float* __restrict__ z, const float* __restrict__ cond,
          const float* __restrict__ fiw, const float* __restrict__ fib,
          const float* __restrict__ bih1, const float* __restrict__ bhh1,
          const float* __restrict__ ob1,  const float* __restrict__ ow2,
          const float* __restrict__ ob2,
          const unsigned short* __restrict__ wsb, float* __restrict__ cws,
          const int* __restrict__ seqp, float* __restrict__ out){
  __shared__ __align__(16) char smem[LDS_TOTAL];
  unsigned short* Xl  = (unsigned short*)(smem + L_X);
  unsigned short* Hl  = (unsigned short*)(smem + L_H);
  float*          HIDl= (float*)(smem + L_HID);
  float*          OW2l= (float*)(smem + L_OW2);
  float*          OB2l= (float*)(smem + L_OB2);

  const int tid = threadIdx.x, wv = tid >> 6, lane = tid & 63;
  const int bid = blockIdx.x;
  const int row0 = bid * BROWS;
  const int T = *seqp;

  const unsigned short* pk0i = wsb;
  const unsigned short* pk1i = wsb + (size_t)PK0_ELEMS;
  const unsigned short* pkoi = wsb + (size_t)PK0_ELEMS + (size_t)PK1_ELEMS;

  {
    int r = tid >> 3, seg = tid & 7;
    int gr = row0 + r;
    for (int c = seg*13; c < seg*13 + 13; ++c) {
      float v;
      if (c < 3)        v = cond[gr*6 + c];
      else if (c < 67)  v = z[gr*64 + (c - 3)];
      else if (c < 73)  v = cond[gr*6 + (c - 67)];
      else if (c == 73) v = 1.0f;
      else              v = 0.f;
      Xl[r*XSTR + c] = f2bf(v);
    }
  }
  if (tid < 384) OW2l[tid] = ow2[tid];
  if (tid < 3)   OB2l[tid] = ob2[tid];

  {
    int r = tid >> 3, ub = (tid & 7) * 32;
    int gr = row0 + r;
    #pragma unroll 1
    for (int u = ub; u < ub + 32; ++u) {
      float s0 = fib[u], s1 = fib[256 + u];
      const float* w0r = fiw + (size_t)u * 70;
      const float* w1r = fiw + (size_t)(256 + u) * 70;
      for (int jj = 0; jj < 64; ++jj) { float xv = z[gr*64 + jj]; s0 += xv * w0r[jj]; s1 += xv * w1r[jj]; }
      for (int jj = 0; jj < 6;  ++jj) { float xv = cond[gr*6 + jj]; s0 += xv * w0r[64 + jj]; s1 += xv * w1r[64 + jj]; }
      Hl[0*HBUF + r*HSTR + u] = f2bf(s0);
      Hl[1*HBUF + r*HSTR + u] = f2bf(s1);
    }
  }

  float bias1r[8];
  #pragma unroll
  for (int p = 0; p < 2; ++p) {
    int u = wv*32 + p*16 + (lane & 15);
    #pragma unroll
    for (int g = 0; g < 4; ++g)
      bias1r[p*4 + g] = bih1[g*256 + u] + bhh1[g*256 + u];
  }
  float ob1r = ob1[wv*16 + (lane & 15)];

  // fallback path: c in registers (spills, R13 behavior)
  float c0s[CWS ? 1 : 32], c1s[CWS ? 1 : 32];
  if constexpr (!CWS) {
    #pragma unroll
    for (int i = 0; i < 32; ++i) { c0s[i] = 0.f; c1s[i] = 0.f; }
  }

  __syncthreads();

  const int arow = lane & 15, koff = (lane >> 4) * 8;

  int ia = 0, ib = 1, ic = 2;

  for (int t = 0; t < T; ++t) {
    const unsigned short* Ha = Hl + ia*HBUF;
    const unsigned short* Hb = Hl + ib*HBUF;
    unsigned short*       Hc = Hl + ic*HBUF;
    unsigned short*       HaW= Hl + ia*HBUF;

    // ===== M1 =====
    #pragma unroll
    for (int p = 0; p < 2; ++p) {
      const unsigned short* wb = pk0i + ((size_t)((wv*2 + p)*NKT0)*64 + lane)*8;

      f32x4 cc[4];
      if constexpr (CWS) {
        const int pc = p;   // pass index 0,1
        #pragma unroll
        for (int i4 = 0; i4 < 4; ++i4)
          cc[i4] = __builtin_nontemporal_load(
              (const f32x4*)(cws + ((((size_t)bid*4 + pc)*4 + i4)*NTHR + tid)*4));
      }

      f32x4 acc[4][4];
      #pragma unroll
      for (int mt = 0; mt < 4; ++mt)
        #pragma unroll
        for (int g = 0; g < 4; ++g) acc[mt][g] = (f32x4){0.f, 0.f, 0.f, 0.f};

      #pragma unroll
      for (int kt = 0; kt < NKT0; ++kt) {
        short8 w[4];
        #pragma unroll
        for (int g = 0; g < 4; ++g)
          w[g] = *(const short8*)(wb + (size_t)g*(16*NKT0*512) + (size_t)kt*512);
        short8 a[4];
        if (kt < 3) {
          #pragma unroll
          for (int mt = 0; mt < 4; ++mt)
            a[mt] = *(const short8*)(Xl + (mt*16 + arow)*XSTR + kt*32 + koff);
        } else {
          #pragma unroll
          for (int mt = 0; mt < 4; ++mt)
            a[mt] = *(const short8*)(Ha + (mt*16 + arow)*HSTR + (kt - 3)*32 + koff);
        }
        #pragma unroll
        for (int g = 0; g < 4; ++g)
          #pragma unroll
          for (int mt = 0; mt < 4; ++mt)
            acc[mt][g] = __builtin_amdgcn_mfma_f32_16x16x32_bf16(a[mt], w[g], acc[mt][g], 0, 0, 0);
      }

      const int u = wv*32 + p*16 + (lane & 15);
      #pragma unroll
      for (int mt = 0; mt < 4; ++mt) {
        #pragma unroll
        for (int q = 0; q < 4; ++q) {
          float iv = sigm(acc[mt][0][q]);
          float fv = sigm(acc[mt][1][q]);
          float gv = ftanh(acc[mt][2][q]);
          float ov = sigm(acc[mt][3][q]);
          float cold = CWS ? cc[mt][q] : c0s[(p*4 + mt)*4 + q];
          float cn = fv * cold + iv * gv;
          if constexpr (CWS) cc[mt][q] = cn; else c0s[(p*4 + mt)*4 + q] = cn;
          float hn = ov * ftanh(cn);
          int r = mt*16 + ((lane >> 4) << 2) + q;
          Hc[r*HSTR + u] = f2bf(hn);
        }
      }
      if constexpr (CWS) {
        const int pc = p;
        #pragma unroll
        for (int i4 = 0; i4 < 4; ++i4)
          __builtin_nontemporal_store(cc[i4],
              (f32x4*)(cws + ((((size_t)bid*4 + pc)*4 + i4)*NTHR + tid)*4));
      }
    }
    __syncthreads();  // B1

    // ===== M2 =====
    #pragma unroll
    for (int p = 0; p < 2; ++p) {
      const unsigned short* wb = pk1i + ((size_t)((wv*2 + p)*NKT1)*64 + lane)*8;

      f32x4 cc[4];
      if constexpr (CWS) {
        const int pc = 2 + p;   // pass index 2,3
        #pragma unroll
        for (int i4 = 0; i4 < 4; ++i4)
          cc[i4] = __builtin_nontemporal_load(
              (const f32x4*)(cws + ((((size_t)bid*4 + pc)*4 + i4)*NTHR + tid)*4));
      }

      f32x4 acc[4][4];
      #pragma unroll
      for (int mt = 0; mt < 4; ++mt)
        #pragma unroll
        for (int g = 0; g < 4; ++g) {
          float b = bias1r[p*4 + g];
          acc[mt][g] = (f32x4){b, b, b, b};
        }

      #pragma unroll
      for (int kt = 0; kt < NKT1; ++kt) {
        short8 w[4];
        #pragma unroll
        for (int g = 0; g < 4; ++g)
          w[g] = *(const short8*)(wb + (size_t)g*(16*NKT1*512) + (size_t)kt*512);
        short8 a[4];
        if (kt < 8) {
          #pragma unroll
          for (int mt = 0; mt < 4; ++mt)
            a[mt] = *(const short8*)(Hc + (mt*16 + arow)*HSTR + kt*32 + koff);
        } else {
          #pragma unroll
          for (int mt = 0; mt < 4; ++mt)
            a[mt] = *(const short8*)(Hb + (mt*16 + arow)*HSTR + (kt - 8)*32 + koff);
        }
        #pragma unroll
        for (int g = 0; g < 4; ++g)
          #pragma unroll
          for (int mt = 0; mt < 4; ++mt)
            acc[mt][g] = __builtin_amdgcn_mfma_f32_16x16x32_bf16(a[mt], w[g], acc[mt][g], 0, 0, 0);
      }

      const int u = wv*32 + p*16 + (lane & 15);
      #pragma unroll
      for (int mt = 0; mt < 4; ++mt) {
        #pragma unroll
        for (int q = 0; q < 4; ++q) {
          float iv = sigm(acc[mt][0][q]);
          float fv = sigm(acc[mt][1][q]);
          float gv = ftanh(acc[mt][2][q]);
          float ov = sigm(acc[mt][3][q]);
          float cold = CWS ? cc[mt][q] : c1s[(p*4 + mt)*4 + q];
          float cn = fv * cold + iv * gv;
          if constexpr (CWS) cc[mt][q] = cn; else c1s[(p*4 + mt)*4 + q] = cn;
          float hn = ov * ftanh(cn);
          int r = mt*16 + ((lane >> 4) << 2) + q;
          HaW[r*HSTR + u] = f2bf(hn);
        }
      }
      if constexpr (CWS) {
        const int pc = 2 + p;
        #pragma unroll
        for (int i4 = 0; i4 < 4; ++i4)
          __builtin_nontemporal_store(cc[i4],
              (f32x4*)(cws + ((((size_t)bid*4 + pc)*4 + i4)*NTHR + tid)*4));
      }
    }
    __syncthreads();  // B2

    // ===== M3 =====
    {
      const unsigned short* wb = pkoi + ((size_t)(wv*NKTO)*64 + lane)*8;
      f32x4 acc3[4];
      #pragma unroll
      for (int mt = 0; mt < 4; ++mt) acc3[mt] = (f32x4){ob1r, ob1r, ob1r, ob1r};

      #pragma unroll
      for (int kt = 0; kt < NKTO; ++kt) {
        const short8 bw = *(const short8*)(wb + (size_t)kt*512);
        short8 a[4];
        #pragma unroll
        for (int mt = 0; mt < 4; ++mt)
          a[mt] = *(const short8*)(HaW + (mt*16 + arow)*HSTR + kt*32 + koff);
        #pragma unroll
        for (int mt = 0; mt < 4; ++mt)
          acc3[mt] = __builtin_amdgcn_mfma_f32_16x16x32_bf16(a[mt], bw, acc3[mt], 0, 0, 0);
      }
      const int uh = wv*16 + (lane & 15);
      #pragma unroll
      for (int mt = 0; mt < 4; ++mt)
        #pragma unroll
        for (int q = 0; q < 4; ++q) {
          float hv = fmaxf(acc3[mt][q], 0.f);
          int r = mt*16 + ((lane >> 4) << 2) + q;
          HIDl[r*HIDSTR + uh] = hv;
        }
    }
    __syncthreads();  // B3

    // ===== M4 =====
    {
      int r = tid >> 3, e = tid & 7;
      const float* hrow = HIDl + r*HIDSTR + e*16;
      float s0 = 0.f, s1 = 0.f, s2 = 0.f;
      #pragma unroll
      for (int k = 0; k < 16; ++k) {
        float hv = hrow[k];
        int kk = e*16 + k;
        s0 += hv * OW2l[kk];
        s1 += hv * OW2l[128 + kk];
        s2 += hv * OW2l[256 + kk];
      }
      #pragma unroll
      for (int d = 4; d; d >>= 1) {
        s0 += __shfl_down(s0, d, 8);
        s1 += __shfl_down(s1, d, 8);
        s2 += __shfl_down(s2, d, 8);
      }
      if (e == 0) {
        s0 += OB2l[0]; s1 += OB2l[1]; s2 += OB2l[2];
        int gr = row0 + r;
        float* orow = out + (size_t)gr * (T*3) + t*3;
        orow[0] = s0; orow[1] = s1; orow[2] = s2;
        Xl[r*XSTR + 0] = f2bf(s0);
        Xl[r*XSTR + 1] = f2bf(s1);
        Xl[r*XSTR + 2] = f2bf(s2);
      }
    }
    __syncthreads();  // B4

    int tmp = ia; ia = ic; ic = ib; ib = tmp;
  }
}

extern "C" void kernel_launch(void* const* d_in, const int* in_sizes, int n_in,
                              void* d_out, int out_size, void* d_ws, size_t ws_size,
                              hipStream_t stream){
  const float* z    = (const float*)d_in[0];
  const float* cond = (const float*)d_in[1];
  const float* fiw  = (const float*)d_in[2];
  const float* fib  = (const float*)d_in[3];
  const float* wih0 = (const float*)d_in[4];
  const float* whh0 = (const float*)d_in[5];
  const float* bih0 = (const float*)d_in[6];
  const float* bhh0 = (const float*)d_in[7];
  const float* wih1 = (const float*)d_in[8];
  const float* whh1 = (const float*)d_in[9];
  const float* bih1 = (const float*)d_in[10];
  const float* bhh1 = (const float*)d_in[11];
  const float* ow1  = (const float*)d_in[12];
  const float* ob1  = (const float*)d_in[13];
  const float* ow2  = (const float*)d_in[14];
  const float* ob2  = (const float*)d_in[15];
  const int*   seqp = (const int*)d_in[16];
  unsigned short* wsb = (unsigned short*)d_ws;
  float* outp = (float*)d_out;

  int packtot = PK0_ELEMS + PK1_ELEMS + PKO_ELEMS;
  pack_weights<<<(packtot + 255)/256, 256, 0, stream>>>(wih0, whh0, bih0, bhh0,
                                                        wih1, whh1, ow1, wsb);
  if (ws_size >= WS_NEED) {
    float* cws = (float*)((char*)d_ws + CWS_OFF_BYTES);
    hipMemsetAsync(cws, 0, CWS_FLOATS*4, stream);
    traj_main<1><<<16384/BROWS, NTHR, 0, stream>>>(z, cond, fiw, fib, bih1, bhh1,
                                                   ob1, ow2, ob2, wsb, cws, seqp, outp);
  } else {
    traj_main<0><<<16384/BROWS, NTHR, 0, stream>>>(z, cond, fiw, fib, bih1, bhh1,
                                                   ob1, ow2, ob2, wsb, nullptr, seqp, outp);
  }
}

// Round 16
// 7534.354 us; speedup vs baseline: 1.0112x; 1.0112x over previous
//
#include <hip/hip_runtime.h>
#include <hip/hip_bf16.h>

typedef short short8 __attribute__((ext_vector_type(8)));
typedef float f32x4 __attribute__((ext_vector_type(4)));

#define BROWS 64
#define NTHR  512
#define XK    96
#define XSTR  104
#define HSTR  264
#define HIDSTR 129
#define NKT0  11
#define NKT1  16
#define NKTO  8
#define PK0_ELEMS (64*NKT0*512)
#define PK1_ELEMS (64*NKT1*512)
#define PKO_ELEMS (8*NKTO*512)

// LDS layout (bytes) — 149,264 B, STATIC
#define L_X    0
#define L_H    13312
#define HBUF   (BROWS*HSTR)
#define HBUF_B (HBUF*2)
#define L_HID  (L_H + 3*HBUF_B)      // 114688 : [64][129] f32
#define L_OW2  (L_HID + BROWS*HIDSTR*4) // 147712
#define L_OB2  (L_OW2 + 1536)        // 149248
#define LDS_TOTAL 149264

__device__ inline unsigned short f2bf(float x){
  unsigned u = __float_as_uint(x);
  u += 0x7FFFu + ((u >> 16) & 1u);
  return (unsigned short)(u >> 16);
}
__device__ inline float bf2f(unsigned short s){ return __uint_as_float(((unsigned)s) << 16); }
__device__ inline float sigm(float x){ return 1.f / (1.f + __expf(-x)); }
__device__ inline float ftanh(float x){ float e = __expf(2.f*x); return 1.f - 2.f/(e + 1.f); }

// ---------------- weight pre-pack (identical to R13) ----------------
__global__ void pack_weights(const float* __restrict__ wih0, const float* __restrict__ whh0,
                             const float* __restrict__ bih0, const float* __restrict__ bhh0,
                             const float* __restrict__ wih1, const float* __restrict__ whh1,
                             const float* __restrict__ ow1,
                             unsigned short* __restrict__ wsb){
  int idx = blockIdx.x * blockDim.x + threadIdx.x;
  int total = PK0_ELEMS + PK1_ELEMS + PKO_ELEMS;
  if (idx >= total) return;
  float w;
  size_t off;
  if (idx < PK0_ELEMS) {
    int nt = idx / (NKT0*512), rem = idx % (NKT0*512), kt = rem / 512, li = rem % 512;
    int lane = li >> 3, j = li & 7;
    int n = lane & 15, k = ((lane >> 4) << 3) + j;
    int Kg = kt*32 + k, g = nt*16 + n;
    if (Kg < 73)        w = wih0[g*73 + Kg];
    else if (Kg == 73)  w = bih0[g] + bhh0[g];
    else if (Kg < XK)   w = 0.f;
    else                w = whh0[g*256 + (Kg - XK)];
    off = ((size_t)(nt*NKT0 + kt)*64 + lane)*8 + j;
  } else if (idx < PK0_ELEMS + PK1_ELEMS) {
    int i2 = idx - PK0_ELEMS;
    int nt = i2 / (NKT1*512), rem = i2 % (NKT1*512), kt = rem / 512, li = rem % 512;
    int lane = li >> 3, j = li & 7;
    int n = lane & 15, k = ((lane >> 4) << 3) + j;
    int Kg = kt*32 + k, g = nt*16 + n;
    w = (Kg < 256) ? wih1[g*256 + Kg] : whh1[g*256 + (Kg - 256)];
    off = (size_t)PK0_ELEMS + ((size_t)(nt*NKT1 + kt)*64 + lane)*8 + j;
  } else {
    int i2 = idx - PK0_ELEMS - PK1_ELEMS;
    int nt = i2 / (NKTO*512), rem = i2 % (NKTO*512), kt = rem / 512, li = rem % 512;
    int lane = li >> 3, j = li & 7;
    int n = lane & 15, k = ((lane >> 4) << 3) + j;
    int Kg = kt*32 + k, uh = nt*16 + n;
    w = ow1[uh*256 + Kg];
    off = (size_t)PK0_ELEMS + (size_t)PK1_ELEMS + ((size_t)(nt*NKTO + kt)*64 + lane)*8 + j;
  }
  wsb[off] = f2bf(w);
}

// ---------------- persistent rollout kernel ----------------
// R1-R15: compiler always budgets VGPR_total = 65536/NTHR (2-blocks/CU target),
// immune to every attribute. At NTHR=512/BROWS=64 the loop-carried state
// acc(64)+c(64)=128 fills the whole file -> forced c-spills (0.48GB/launch) ->
// L2 scratch churn -> ~50% weight miss -> latency-bound at 12% MfmaUtil.
// Crowbar: pin c-state into AGPRs with inline-asm "+a" constraints at the loop
// back-edge. The allocator cannot refuse asm constraints; real occupancy is
// LDS-bound at 2 waves/SIMD (512 regs/lane-slot available), so 128v + 64a fits
// with room to spare and c NEVER touches scratch.
__global__ void __launch_bounds__(NTHR)
traj_main(const float* __restrict__ z, const float* __restrict__ cond,
          const float* __restrict__ fiw, const float* __restrict__ fib,
          const float* __restrict__ bih1, const float* __restrict__ bhh1,
          const float* __restrict__ ob1,  const float* __restrict__ ow2,
          const float* __restrict__ ob2,
          const unsigned short* __restrict__ wsb, const int* __restrict__ seqp,
          float* __restrict__ out){
  __shared__ __align__(16) char smem[LDS_TOTAL];
  unsigned short* Xl  = (unsigned short*)(smem + L_X);
  unsigned short* Hl  = (unsigned short*)(smem + L_H);
  float*          HIDl= (float*)(smem + L_HID);
  float*          OW2l= (float*)(smem + L_OW2);
  float*          OB2l= (float*)(smem + L_OB2);

  const int tid = threadIdx.x, wv = tid >> 6, lane = tid & 63;
  const int bid = blockIdx.x;
  const int row0 = bid * BROWS;
  const int T = *seqp;

  const unsigned short* pk0i = wsb;
  const unsigned short* pk1i = wsb + (size_t)PK0_ELEMS;
  const unsigned short* pkoi = wsb + (size_t)PK0_ELEMS + (size_t)PK1_ELEMS;

  {
    int r = tid >> 3, seg = tid & 7;
    int gr = row0 + r;
    for (int c = seg*13; c < seg*13 + 13; ++c) {
      float v;
      if (c < 3)        v = cond[gr*6 + c];
      else if (c < 67)  v = z[gr*64 + (c - 3)];
      else if (c < 73)  v = cond[gr*6 + (c - 67)];
      else if (c == 73) v = 1.0f;
      else              v = 0.f;
      Xl[r*XSTR + c] = f2bf(v);
    }
  }
  if (tid < 384) OW2l[tid] = ow2[tid];
  if (tid < 3)   OB2l[tid] = ob2[tid];

  {
    int r = tid >> 3, ub = (tid & 7) * 32;
    int gr = row0 + r;
    #pragma unroll 1
    for (int u = ub; u < ub + 32; ++u) {
      float s0 = fib[u], s1 = fib[256 + u];
      const float* w0r = fiw + (size_t)u * 70;
      const float* w1r = fiw + (size_t)(256 + u) * 70;
      for (int jj = 0; jj < 64; ++jj) { float xv = z[gr*64 + jj]; s0 += xv * w0r[jj]; s1 += xv * w1r[jj]; }
      for (int jj = 0; jj < 6;  ++jj) { float xv = cond[gr*6 + jj]; s0 += xv * w0r[64 + jj]; s1 += xv * w1r[64 + jj]; }
      Hl[0*HBUF + r*HSTR + u] = f2bf(s0);
      Hl[1*HBUF + r*HSTR + u] = f2bf(s1);
    }
  }

  float bias1r[8];
  #pragma unroll
  for (int p = 0; p < 2; ++p) {
    int u = wv*32 + p*16 + (lane & 15);
    #pragma unroll
    for (int g = 0; g < 4; ++g)
      bias1r[p*4 + g] = bih1[g*256 + u] + bhh1[g*256 + u];
  }
  float ob1r = ob1[wv*16 + (lane & 15)];

  // ---- c-state as f32x4 quads, statically indexed (quad = p*4+mt), AGPR-pinned
  f32x4 c0q[8], c1q[8];
  #pragma unroll
  for (int i = 0; i < 8; ++i) { c0q[i] = (f32x4){0.f,0.f,0.f,0.f}; c1q[i] = (f32x4){0.f,0.f,0.f,0.f}; }
  // establish AGPR residence before the loop
  asm volatile("" : "+a"(c0q[0]),"+a"(c0q[1]),"+a"(c0q[2]),"+a"(c0q[3]),
                    "+a"(c0q[4]),"+a"(c0q[5]),"+a"(c0q[6]),"+a"(c0q[7]),
                    "+a"(c1q[0]),"+a"(c1q[1]),"+a"(c1q[2]),"+a"(c1q[3]),
                    "+a"(c1q[4]),"+a"(c1q[5]),"+a"(c1q[6]),"+a"(c1q[7]));

  __syncthreads();

  const int arow = lane & 15, koff = (lane >> 4) * 8;

  int ia = 0, ib = 1, ic = 2;

  for (int t = 0; t < T; ++t) {
    const unsigned short* Ha = Hl + ia*HBUF;
    const unsigned short* Hb = Hl + ib*HBUF;
    unsigned short*       Hc = Hl + ic*HBUF;
    unsigned short*       HaW= Hl + ia*HBUF;

    // ===== M1: gates0 (bias in X col 73); h0n -> H[ic] =====
    #pragma unroll
    for (int p = 0; p < 2; ++p) {
      const unsigned short* wb = pk0i + ((size_t)((wv*2 + p)*NKT0)*64 + lane)*8;

      short8 wh[2][4];
      #pragma unroll
      for (int g = 0; g < 4; ++g)
        wh[0][g] = *(const short8*)(wb + (size_t)g*(16*NKT0*512));

      f32x4 acc[4][4];
      #pragma unroll
      for (int mt = 0; mt < 4; ++mt)
        #pragma unroll
        for (int g = 0; g < 4; ++g) acc[mt][g] = (f32x4){0.f, 0.f, 0.f, 0.f};

      #pragma unroll
      for (int kt = 0; kt < NKT0; ++kt) {
        const int cb = kt & 1, nb = cb ^ 1;
        if (kt + 1 < NKT0) {
          #pragma unroll
          for (int g = 0; g < 4; ++g)
            wh[nb][g] = *(const short8*)(wb + (size_t)g*(16*NKT0*512) + (size_t)(kt+1)*512);
        }
        short8 a[4];
        if (kt < 3) {
          #pragma unroll
          for (int mt = 0; mt < 4; ++mt)
            a[mt] = *(const short8*)(Xl + (mt*16 + arow)*XSTR + kt*32 + koff);
        } else {
          #pragma unroll
          for (int mt = 0; mt < 4; ++mt)
            a[mt] = *(const short8*)(Ha + (mt*16 + arow)*HSTR + (kt - 3)*32 + koff);
        }
        #pragma unroll
        for (int g = 0; g < 4; ++g)
          #pragma unroll
          for (int mt = 0; mt < 4; ++mt)
            acc[mt][g] = __builtin_amdgcn_mfma_f32_16x16x32_bf16(a[mt], wh[cb][g], acc[mt][g], 0, 0, 0);
      }

      const int u = wv*32 + p*16 + (lane & 15);
      #pragma unroll
      for (int mt = 0; mt < 4; ++mt) {
        #pragma unroll
        for (int q = 0; q < 4; ++q) {
          float iv = sigm(acc[mt][0][q]);
          float fv = sigm(acc[mt][1][q]);
          float gv = ftanh(acc[mt][2][q]);
          float ov = sigm(acc[mt][3][q]);
          float cn = fv * c0q[p*4 + mt][q] + iv * gv;
          c0q[p*4 + mt][q] = cn;
          float hn = ov * ftanh(cn);
          int r = mt*16 + ((lane >> 4) << 2) + q;
          Hc[r*HSTR + u] = f2bf(hn);
        }
      }
    }
    __syncthreads();  // B1

    // ===== M2: gates1 (+b); h1n -> H[ia] =====
    #pragma unroll
    for (int p = 0; p < 2; ++p) {
      const unsigned short* wb = pk1i + ((size_t)((wv*2 + p)*NKT1)*64 + lane)*8;

      short8 wh[2][4];
      #pragma unroll
      for (int g = 0; g < 4; ++g)
        wh[0][g] = *(const short8*)(wb + (size_t)g*(16*NKT1*512));

      f32x4 acc[4][4];
      #pragma unroll
      for (int mt = 0; mt < 4; ++mt)
        #pragma unroll
        for (int g = 0; g < 4; ++g) {
          float b = bias1r[p*4 + g];
          acc[mt][g] = (f32x4){b, b, b, b};
        }

      #pragma unroll
      for (int kt = 0; kt < NKT1; ++kt) {
        const int cb = kt & 1, nb = cb ^ 1;
        if (kt + 1 < NKT1) {
          #pragma unroll
          for (int g = 0; g < 4; ++g)
            wh[nb][g] = *(const short8*)(wb + (size_t)g*(16*NKT1*512) + (size_t)(kt+1)*512);
        }
        short8 a[4];
        if (kt < 8) {
          #pragma unroll
          for (int mt = 0; mt < 4; ++mt)
            a[mt] = *(const short8*)(Hc + (mt*16 + arow)*HSTR + kt*32 + koff);
        } else {
          #pragma unroll
          for (int mt = 0; mt < 4; ++mt)
            a[mt] = *(const short8*)(Hb + (mt*16 + arow)*HSTR + (kt - 8)*32 + koff);
        }
        #pragma unroll
        for (int g = 0; g < 4; ++g)
          #pragma unroll
          for (int mt = 0; mt < 4; ++mt)
            acc[mt][g] = __builtin_amdgcn_mfma_f32_16x16x32_bf16(a[mt], wh[cb][g], acc[mt][g], 0, 0, 0);
      }

      const int u = wv*32 + p*16 + (lane & 15);
      #pragma unroll
      for (int mt = 0; mt < 4; ++mt) {
        #pragma unroll
        for (int q = 0; q < 4; ++q) {
          float iv = sigm(acc[mt][0][q]);
          float fv = sigm(acc[mt][1][q]);
          float gv = ftanh(acc[mt][2][q]);
          float ov = sigm(acc[mt][3][q]);
          float cn = fv * c1q[p*4 + mt][q] + iv * gv;
          c1q[p*4 + mt][q] = cn;
          float hn = ov * ftanh(cn);
          int r = mt*16 + ((lane >> 4) << 2) + q;
          HaW[r*HSTR + u] = f2bf(hn);
        }
      }
    }
    __syncthreads();  // B2

    // ===== M3: hid = relu(h1n @ out_w1^T + ob1) -> LDS fp32 =====
    {
      const unsigned short* wb = pkoi + ((size_t)(wv*NKTO)*64 + lane)*8;
      short8 wh[2];
      wh[0] = *(const short8*)(wb);

      f32x4 acc3[4];
      #pragma unroll
      for (int mt = 0; mt < 4; ++mt) acc3[mt] = (f32x4){ob1r, ob1r, ob1r, ob1r};

      #pragma unroll
      for (int kt = 0; kt < NKTO; ++kt) {
        const int cb = kt & 1, nb = cb ^ 1;
        if (kt + 1 < NKTO)
          wh[nb] = *(const short8*)(wb + (size_t)(kt+1)*512);
        short8 a[4];
        #pragma unroll
        for (int mt = 0; mt < 4; ++mt)
          a[mt] = *(const short8*)(HaW + (mt*16 + arow)*HSTR + kt*32 + koff);
        #pragma unroll
        for (int mt = 0; mt < 4; ++mt)
          acc3[mt] = __builtin_amdgcn_mfma_f32_16x16x32_bf16(a[mt], wh[cb], acc3[mt], 0, 0, 0);
      }
      const int uh = wv*16 + (lane & 15);
      #pragma unroll
      for (int mt = 0; mt < 4; ++mt)
        #pragma unroll
        for (int q = 0; q < 4; ++q) {
          float hv = fmaxf(acc3[mt][q], 0.f);
          int r = mt*16 + ((lane >> 4) << 2) + q;
          HIDl[r*HIDSTR + uh] = hv;
        }
    }
    __syncthreads();  // B3

    // ===== M4: out = hid @ out_w2^T + ob2 =====
    {
      int r = tid >> 3, e = tid & 7;
      const float* hrow = HIDl + r*HIDSTR + e*16;
      float s0 = 0.f, s1 = 0.f, s2 = 0.f;
      #pragma unroll
      for (int k = 0; k < 16; ++k) {
        float hv = hrow[k];
        int kk = e*16 + k;
        s0 += hv * OW2l[kk];
        s1 += hv * OW2l[128 + kk];
        s2 += hv * OW2l[256 + kk];
      }
      #pragma unroll
      for (int d = 4; d; d >>= 1) {
        s0 += __shfl_down(s0, d, 8);
        s1 += __shfl_down(s1, d, 8);
        s2 += __shfl_down(s2, d, 8);
      }
      if (e == 0) {
        s0 += OB2l[0]; s1 += OB2l[1]; s2 += OB2l[2];
        int gr = row0 + r;
        float* orow = out + (size_t)gr * (T*3) + t*3;
        orow[0] = s0; orow[1] = s1; orow[2] = s2;
        Xl[r*XSTR + 0] = f2bf(s0);
        Xl[r*XSTR + 1] = f2bf(s1);
        Xl[r*XSTR + 2] = f2bf(s2);
      }
    }
    __syncthreads();  // B4

    // re-pin c-state into AGPRs at the loop back-edge: loop-carried values
    // MUST reside in AGPRs here, so the allocator cannot spill them to scratch.
    asm volatile("" : "+a"(c0q[0]),"+a"(c0q[1]),"+a"(c0q[2]),"+a"(c0q[3]),
                      "+a"(c0q[4]),"+a"(c0q[5]),"+a"(c0q[6]),"+a"(c0q[7]),
                      "+a"(c1q[0]),"+a"(c1q[1]),"+a"(c1q[2]),"+a"(c1q[3]),
                      "+a"(c1q[4]),"+a"(c1q[5]),"+a"(c1q[6]),"+a"(c1q[7]));

    int tmp = ia; ia = ic; ic = ib; ib = tmp;
  }
}

extern "C" void kernel_launch(void* const* d_in, const int* in_sizes, int n_in,
                              void* d_out, int out_size, void* d_ws, size_t ws_size,
                              hipStream_t stream){
  const float* z    = (const float*)d_in[0];
  const float* cond = (const float*)d_in[1];
  const float* fiw  = (const float*)d_in[2];
  const float* fib  = (const float*)d_in[3];
  const float* wih0 = (const float*)d_in[4];
  const float* whh0 = (const float*)d_in[5];
  const float* bih0 = (const float*)d_in[6];
  const float* bhh0 = (const float*)d_in[7];
  const float* wih1 = (const float*)d_in[8];
  const float* whh1 = (const float*)d_in[9];
  const float* bih1 = (const float*)d_in[10];
  const float* bhh1 = (const float*)d_in[11];
  const float* ow1  = (const float*)d_in[12];
  const float* ob1  = (const float*)d_in[13];
  const float* ow2  = (const float*)d_in[14];
  const float* ob2  = (const float*)d_in[15];
  const int*   seqp = (const int*)d_in[16];
  unsigned short* wsb = (unsigned short*)d_ws;
  float* outp = (float*)d_out;

  int packtot = PK0_ELEMS + PK1_ELEMS + PKO_ELEMS;
  pack_weights<<<(packtot + 255)/256, 256, 0, stream>>>(wih0, whh0, bih0, bhh0,
                                                        wih1, whh1, ow1, wsb);
  traj_main<<<16384/BROWS, NTHR, 0, stream>>>(z, cond, fiw, fib,
                                              bih1, bhh1,
                                              ob1, ow2, ob2, wsb, seqp, outp);
}

// Round 17
// 5966.628 us; speedup vs baseline: 1.2769x; 1.2627x over previous
//
#include <hip/hip_runtime.h>
#include <hip/hip_bf16.h>

typedef short short8 __attribute__((ext_vector_type(8)));
typedef float f32x4 __attribute__((ext_vector_type(4)));

#define BROWS 64
#define NTHR  512
#define XK    96
#define XSTR  106    // 53 dwords, odd -> conflict-free A-frag reads (was 104 = 52 dw, 8-bank alias)
#define HSTR  266    // 133 dwords, odd -> 16 rows = 16 banks (was 264 = 132 dw ≡ 4 mod 32, 8-way)
#define HIDSTR 129
#define NKT0  11
#define NKT1  16
#define NKTO  8
#define PK0_ELEMS (64*NKT0*512)
#define PK1_ELEMS (64*NKT1*512)
#define PKO_ELEMS (8*NKTO*512)

// LDS layout (bytes) — 150,288 B, STATIC
#define L_X    0
#define L_H    13568                     // X: 64*106*2
#define HBUF   (BROWS*HSTR)              // 17024 ushorts per H buffer
#define HBUF_B (HBUF*2)                  // 34048 B
#define L_HID  (L_H + 3*HBUF_B)          // 115712 : [64][129] f32
#define L_OW2  (L_HID + BROWS*HIDSTR*4)  // 148736
#define L_OB2  (L_OW2 + 1536)            // 150272
#define LDS_TOTAL 150288

__device__ inline unsigned short f2bf(float x){
  unsigned u = __float_as_uint(x);
  u += 0x7FFFu + ((u >> 16) & 1u);
  return (unsigned short)(u >> 16);
}
__device__ inline float bf2f(unsigned short s){ return __uint_as_float(((unsigned)s) << 16); }
__device__ inline float sigm(float x){ return 1.f / (1.f + __expf(-x)); }
__device__ inline float ftanh(float x){ float e = __expf(2.f*x); return 1.f - 2.f/(e + 1.f); }

// ---------------- weight pre-pack (identical to R13; layout independent of LDS strides) ----
__global__ void pack_weights(const float* __restrict__ wih0, const float* __restrict__ whh0,
                             const float* __restrict__ bih0, const float* __restrict__ bhh0,
                             const float* __restrict__ wih1, const float* __restrict__ whh1,
                             const float* __restrict__ ow1,
                             unsigned short* __restrict__ wsb){
  int idx = blockIdx.x * blockDim.x + threadIdx.x;
  int total = PK0_ELEMS + PK1_ELEMS + PKO_ELEMS;
  if (idx >= total) return;
  float w;
  size_t off;
  if (idx < PK0_ELEMS) {
    int nt = idx / (NKT0*512), rem = idx % (NKT0*512), kt = rem / 512, li = rem % 512;
    int lane = li >> 3, j = li & 7;
    int n = lane & 15, k = ((lane >> 4) << 3) + j;
    int Kg = kt*32 + k, g = nt*16 + n;
    if (Kg < 73)        w = wih0[g*73 + Kg];
    else if (Kg == 73)  w = bih0[g] + bhh0[g];
    else if (Kg < XK)   w = 0.f;
    else                w = whh0[g*256 + (Kg - XK)];
    off = ((size_t)(nt*NKT0 + kt)*64 + lane)*8 + j;
  } else if (idx < PK0_ELEMS + PK1_ELEMS) {
    int i2 = idx - PK0_ELEMS;
    int nt = i2 / (NKT1*512), rem = i2 % (NKT1*512), kt = rem / 512, li = rem % 512;
    int lane = li >> 3, j = li & 7;
    int n = lane & 15, k = ((lane >> 4) << 3) + j;
    int Kg = kt*32 + k, g = nt*16 + n;
    w = (Kg < 256) ? wih1[g*256 + Kg] : whh1[g*256 + (Kg - 256)];
    off = (size_t)PK0_ELEMS + ((size_t)(nt*NKT1 + kt)*64 + lane)*8 + j;
  } else {
    int i2 = idx - PK0_ELEMS - PK1_ELEMS;
    int nt = i2 / (NKTO*512), rem = i2 % (NKTO*512), kt = rem / 512, li = rem % 512;
    int lane = li >> 3, j = li & 7;
    int n = lane & 15, k = ((lane >> 4) << 3) + j;
    int Kg = kt*32 + k, uh = nt*16 + n;
    w = ow1[uh*256 + Kg];
    off = (size_t)PK0_ELEMS + (size_t)PK1_ELEMS + ((size_t)(nt*NKTO + kt)*64 + lane)*8 + j;
  }
  wsb[off] = f2bf(w);
}

// ---------------- persistent rollout kernel ----------------
// == R13 (best, 5.72ms) with ONE isolated change: odd-dword LDS row strides.
// R13's SQ_LDS_BANK_CONFLICT = 1.3e8 (~4 extra cy per LDS op): HSTR 264 ushort
// = 132 dw ≡ 4 (mod 32) made A-frag ds_read_b128 an ~8-way bank conflict,
// costing ~7.5k cy/wave/step -- comparable to the MFMA work itself.
// HSTR=266 (133 dw, odd): 16 rows -> 16 distinct banks; quad overlap 2-way (free).
__global__ void __launch_bounds__(NTHR)
__attribute__((amdgpu_num_vgpr(256)))
traj_main(const float* __restrict__ z, const float* __restrict__ cond,
          const float* __restrict__ fiw, const float* __restrict__ fib,
          const float* __restrict__ bih1, const float* __restrict__ bhh1,
          const float* __restrict__ ob1,  const float* __restrict__ ow2,
          const float* __restrict__ ob2,
          const unsigned short* __restrict__ wsb, const int* __restrict__ seqp,
          float* __restrict__ out){
  __shared__ __align__(16) char smem[LDS_TOTAL];
  unsigned short* Xl  = (unsigned short*)(smem + L_X);
  unsigned short* Hl  = (unsigned short*)(smem + L_H);
  float*          HIDl= (float*)(smem + L_HID);
  float*          OW2l= (float*)(smem + L_OW2);
  float*          OB2l= (float*)(smem + L_OB2);

  const int tid = threadIdx.x, wv = tid >> 6, lane = tid & 63;
  const int bid = blockIdx.x;
  const int row0 = bid * BROWS;
  const int T = *seqp;

  const unsigned short* pk0i = wsb;
  const unsigned short* pk1i = wsb + (size_t)PK0_ELEMS;
  const unsigned short* pkoi = wsb + (size_t)PK0_ELEMS + (size_t)PK1_ELEMS;

  {
    int r = tid >> 3, seg = tid & 7;
    int gr = row0 + r;
    for (int c = seg*13; c < seg*13 + 13; ++c) {
      float v;
      if (c < 3)        v = cond[gr*6 + c];
      else if (c < 67)  v = z[gr*64 + (c - 3)];
      else if (c < 73)  v = cond[gr*6 + (c - 67)];
      else if (c == 73) v = 1.0f;
      else              v = 0.f;
      Xl[r*XSTR + c] = f2bf(v);
    }
  }
  if (tid < 384) OW2l[tid] = ow2[tid];
  if (tid < 3)   OB2l[tid] = ob2[tid];

  {
    int r = tid >> 3, ub = (tid & 7) * 32;
    int gr = row0 + r;
    #pragma unroll 1
    for (int u = ub; u < ub + 32; ++u) {
      float s0 = fib[u], s1 = fib[256 + u];
      const float* w0r = fiw + (size_t)u * 70;
      const float* w1r = fiw + (size_t)(256 + u) * 70;
      for (int jj = 0; jj < 64; ++jj) { float xv = z[gr*64 + jj]; s0 += xv * w0r[jj]; s1 += xv * w1r[jj]; }
      for (int jj = 0; jj < 6;  ++jj) { float xv = cond[gr*6 + jj]; s0 += xv * w0r[64 + jj]; s1 += xv * w1r[64 + jj]; }
      Hl[0*HBUF + r*HSTR + u] = f2bf(s0);
      Hl[1*HBUF + r*HSTR + u] = f2bf(s1);
    }
  }

  float bias1r[8];
  #pragma unroll
  for (int p = 0; p < 2; ++p) {
    int u = wv*32 + p*16 + (lane & 15);
    #pragma unroll
    for (int g = 0; g < 4; ++g)
      bias1r[p*4 + g] = bih1[g*256 + u] + bhh1[g*256 + u];
  }
  float ob1r = ob1[wv*16 + (lane & 15)];

  float c0s[32], c1s[32];
  #pragma unroll
  for (int i = 0; i < 32; ++i) { c0s[i] = 0.f; c1s[i] = 0.f; }

  __syncthreads();

  const int arow = lane & 15, koff = (lane >> 4) * 8;

  int ia = 0, ib = 1, ic = 2;

  for (int t = 0; t < T; ++t) {
    const unsigned short* Ha = Hl + ia*HBUF;
    const unsigned short* Hb = Hl + ib*HBUF;
    unsigned short*       Hc = Hl + ic*HBUF;
    unsigned short*       HaW= Hl + ia*HBUF;

    // ===== M1: gates0 (bias in X col 73); h0n -> H[ic] =====
    #pragma unroll
    for (int p = 0; p < 2; ++p) {
      const unsigned short* wb = pk0i + ((size_t)((wv*2 + p)*NKT0)*64 + lane)*8;

      short8 wh[2][4];
      #pragma unroll
      for (int g = 0; g < 4; ++g)
        wh[0][g] = *(const short8*)(wb + (size_t)g*(16*NKT0*512));

      f32x4 acc[4][4];
      #pragma unroll
      for (int mt = 0; mt < 4; ++mt)
        #pragma unroll
        for (int g = 0; g < 4; ++g) acc[mt][g] = (f32x4){0.f, 0.f, 0.f, 0.f};

      #pragma unroll
      for (int kt = 0; kt < NKT0; ++kt) {
        const int cb = kt & 1, nb = cb ^ 1;
        if (kt + 1 < NKT0) {
          #pragma unroll
          for (int g = 0; g < 4; ++g)
            wh[nb][g] = *(const short8*)(wb + (size_t)g*(16*NKT0*512) + (size_t)(kt+1)*512);
        }
        short8 a[4];
        if (kt < 3) {
          #pragma unroll
          for (int mt = 0; mt < 4; ++mt)
            a[mt] = *(const short8*)(Xl + (mt*16 + arow)*XSTR + kt*32 + koff);
        } else {
          #pragma unroll
          for (int mt = 0; mt < 4; ++mt)
            a[mt] = *(const short8*)(Ha + (mt*16 + arow)*HSTR + (kt - 3)*32 + koff);
        }
        #pragma unroll
        for (int g = 0; g < 4; ++g)
          #pragma unroll
          for (int mt = 0; mt < 4; ++mt)
            acc[mt][g] = __builtin_amdgcn_mfma_f32_16x16x32_bf16(a[mt], wh[cb][g], acc[mt][g], 0, 0, 0);
      }

      const int u = wv*32 + p*16 + (lane & 15);
      #pragma unroll
      for (int mt = 0; mt < 4; ++mt) {
        #pragma unroll
        for (int q = 0; q < 4; ++q) {
          float iv = sigm(acc[mt][0][q]);
          float fv = sigm(acc[mt][1][q]);
          float gv = ftanh(acc[mt][2][q]);
          float ov = sigm(acc[mt][3][q]);
          float cn = fv * c0s[(p*4 + mt)*4 + q] + iv * gv;
          c0s[(p*4 + mt)*4 + q] = cn;
          float hn = ov * ftanh(cn);
          int r = mt*16 + ((lane >> 4) << 2) + q;
          Hc[r*HSTR + u] = f2bf(hn);
        }
      }
    }
    __syncthreads();  // B1

    // ===== M2: gates1 (+b); h1n -> H[ia] =====
    #pragma unroll
    for (int p = 0; p < 2; ++p) {
      const unsigned short* wb = pk1i + ((size_t)((wv*2 + p)*NKT1)*64 + lane)*8;

      short8 wh[2][4];
      #pragma unroll
      for (int g = 0; g < 4; ++g)
        wh[0][g] = *(const short8*)(wb + (size_t)g*(16*NKT1*512));

      f32x4 acc[4][4];
      #pragma unroll
      for (int mt = 0; mt < 4; ++mt)
        #pragma unroll
        for (int g = 0; g < 4; ++g) {
          float b = bias1r[p*4 + g];
          acc[mt][g] = (f32x4){b, b, b, b};
        }

      #pragma unroll
      for (int kt = 0; kt < NKT1; ++kt) {
        const int cb = kt & 1, nb = cb ^ 1;
        if (kt + 1 < NKT1) {
          #pragma unroll
          for (int g = 0; g < 4; ++g)
            wh[nb][g] = *(const short8*)(wb + (size_t)g*(16*NKT1*512) + (size_t)(kt+1)*512);
        }
        short8 a[4];
        if (kt < 8) {
          #pragma unroll
          for (int mt = 0; mt < 4; ++mt)
            a[mt] = *(const short8*)(Hc + (mt*16 + arow)*HSTR + kt*32 + koff);
        } else {
          #pragma unroll
          for (int mt = 0; mt < 4; ++mt)
            a[mt] = *(const short8*)(Hb + (mt*16 + arow)*HSTR + (kt - 8)*32 + koff);
        }
        #pragma unroll
        for (int g = 0; g < 4; ++g)
          #pragma unroll
          for (int mt = 0; mt < 4; ++mt)
            acc[mt][g] = __builtin_amdgcn_mfma_f32_16x16x32_bf16(a[mt], wh[cb][g], acc[mt][g], 0, 0, 0);
      }

      const int u = wv*32 + p*16 + (lane & 15);
      #pragma unroll
      for (int mt = 0; mt < 4; ++mt) {
        #pragma unroll
        for (int q = 0; q < 4; ++q) {
          float iv = sigm(acc[mt][0][q]);
          float fv = sigm(acc[mt][1][q]);
          float gv = ftanh(acc[mt][2][q]);
          float ov = sigm(acc[mt][3][q]);
          float cn = fv * c1s[(p*4 + mt)*4 + q] + iv * gv;
          c1s[(p*4 + mt)*4 + q] = cn;
          float hn = ov * ftanh(cn);
          int r = mt*16 + ((lane >> 4) << 2) + q;
          HaW[r*HSTR + u] = f2bf(hn);
        }
      }
    }
    __syncthreads();  // B2

    // ===== M3: hid = relu(h1n @ out_w1^T + ob1) -> LDS fp32 =====
    {
      const unsigned short* wb = pkoi + ((size_t)(wv*NKTO)*64 + lane)*8;
      short8 wh[2];
      wh[0] = *(const short8*)(wb);

      f32x4 acc3[4];
      #pragma unroll
      for (int mt = 0; mt < 4; ++mt) acc3[mt] = (f32x4){ob1r, ob1r, ob1r, ob1r};

      #pragma unroll
      for (int kt = 0; kt < NKTO; ++kt) {
        const int cb = kt & 1, nb = cb ^ 1;
        if (kt + 1 < NKTO)
          wh[nb] = *(const short8*)(wb + (size_t)(kt+1)*512);
        short8 a[4];
        #pragma unroll
        for (int mt = 0; mt < 4; ++mt)
          a[mt] = *(const short8*)(HaW + (mt*16 + arow)*HSTR + kt*32 + koff);
        #pragma unroll
        for (int mt = 0; mt < 4; ++mt)
          acc3[mt] = __builtin_amdgcn_mfma_f32_16x16x32_bf16(a[mt], wh[cb], acc3[mt], 0, 0, 0);
      }
      const int uh = wv*16 + (lane & 15);
      #pragma unroll
      for (int mt = 0; mt < 4; ++mt)
        #pragma unroll
        for (int q = 0; q < 4; ++q) {
          float hv = fmaxf(acc3[mt][q], 0.f);
          int r = mt*16 + ((lane >> 4) << 2) + q;
          HIDl[r*HIDSTR + uh] = hv;
        }
    }
    __syncthreads();  // B3

    // ===== M4: out = hid @ out_w2^T + ob2 =====
    {
      int r = tid >> 3, e = tid & 7;
      const float* hrow = HIDl + r*HIDSTR + e*16;
      float s0 = 0.f, s1 = 0.f, s2 = 0.f;
      #pragma unroll
      for (int k = 0; k < 16; ++k) {
        float hv = hrow[k];
        int kk = e*16 + k;
        s0 += hv * OW2l[kk];
        s1 += hv * OW2l[128 + kk];
        s2 += hv * OW2l[256 + kk];
      }
      #pragma unroll
      for (int d = 4; d; d >>= 1) {
        s0 += __shfl_down(s0, d, 8);
        s1 += __shfl_down(s1, d, 8);
        s2 += __shfl_down(s2, d, 8);
      }
      if (e == 0) {
        s0 += OB2l[0]; s1 += OB2l[1]; s2 += OB2l[2];
        int gr = row0 + r;
        float* orow = out + (size_t)gr * (T*3) + t*3;
        orow[0] = s0; orow[1] = s1; orow[2] = s2;
        Xl[r*XSTR + 0] = f2bf(s0);
        Xl[r*XSTR + 1] = f2bf(s1);
        Xl[r*XSTR + 2] = f2bf(s2);
      }
    }
    __syncthreads();  // B4

    int tmp = ia; ia = ic; ic = ib; ib = tmp;
  }
}

extern "C" void kernel_launch(void* const* d_in, const int* in_sizes, int n_in,
                              void* d_out, int out_size, void* d_ws, size_t ws_size,
                              hipStream_t stream){
  const float* z    = (const float*)d_in[0];
  const float* cond = (const float*)d_in[1];
  const float* fiw  = (const float*)d_in[2];
  const float* fib  = (const float*)d_in[3];
  const float* wih0 = (const float*)d_in[4];
  const float* whh0 = (const float*)d_in[5];
  const float* bih0 = (const float*)d_in[6];
  const float* bhh0 = (const float*)d_in[7];
  const float* wih1 = (const float*)d_in[8];
  const float* whh1 = (const float*)d_in[9];
  const float* bih1 = (const float*)d_in[10];
  const float* bhh1 = (const float*)d_in[11];
  const float* ow1  = (const float*)d_in[12];
  const float* ob1  = (const float*)d_in[13];
  const float* ow2  = (const float*)d_in[14];
  const float* ob2  = (const float*)d_in[15];
  const int*   seqp = (const int*)d_in[16];
  unsigned short* wsb = (unsigned short*)d_ws;
  float* outp = (float*)d_out;

  int packtot = PK0_ELEMS + PK1_ELEMS + PKO_ELEMS;
  pack_weights<<<(packtot + 255)/256, 256, 0, stream>>>(wih0, whh0, bih0, bhh0,
                                                        wih1, whh1, ow1, wsb);
  traj_main<<<16384/BROWS, NTHR, 0, stream>>>(z, cond, fiw, fib,
                                              bih1, bhh1,
                                              ob1, ow2, ob2, wsb, seqp, outp);
}